// Round 6
// baseline (386.566 us; speedup 1.0000x reference)
//
#include <hip/hip_runtime.h>
#include <hip/hip_bf16.h>
#include <cstdint>

#define N_NODES 100000
#define N_EDGES 600000
#define C_IN    256
#define C_HID   128
#define C_OUT   128
#define LN_EPS  1e-5f
#define NEG_SLOPE 0.01f

#define NSCAN_BLOCKS 391  // ceil(100000/256)

typedef float f32x4 __attribute__((ext_vector_type(4)));
typedef __attribute__((ext_vector_type(8))) short frag_ab;  // 8 bf16 in 4 VGPRs

// ---- fp32 -> bf16 hi/lo split (RTZ hi, residual in lo; ~2^-16 rel total) ----
__device__ __forceinline__ void split2(float f, ushort& h, ushort& l) {
    unsigned u = __float_as_uint(f);
    h = (ushort)(u >> 16);
    float d = f - __uint_as_float(u & 0xFFFF0000u);
    l = (ushort)(__float_as_uint(d) >> 16);
}

__device__ __forceinline__ void split8(const float4& p, const float4& q,
                                       frag_ab& hi, frag_ab& lo) {
    ushort h, l;
    split2(p.x, h, l); hi[0] = (short)h; lo[0] = (short)l;
    split2(p.y, h, l); hi[1] = (short)h; lo[1] = (short)l;
    split2(p.z, h, l); hi[2] = (short)h; lo[2] = (short)l;
    split2(p.w, h, l); hi[3] = (short)h; lo[3] = (short)l;
    split2(q.x, h, l); hi[4] = (short)h; lo[4] = (short)l;
    split2(q.y, h, l); hi[5] = (short)h; lo[5] = (short)l;
    split2(q.z, h, l); hi[6] = (short)h; lo[6] = (short)l;
    split2(q.w, h, l); hi[7] = (short)h; lo[7] = (short)l;
}

// ---------------------------------------------------------------------------
// K_p: pre-split W1/W2 into bf16 hi/lo, tiled in MFMA B-fragment order:
//   frag_index(kc,nf,ks,plane) = ((kc*32 + nf*4 + ks)*2 + plane)*64 + lane
//   value(lane,j) = W[k = kc*128 + ks*32 + (lane>>4)*8 + j][n = nf*16 + (lane&15)]
// One thread per (kc,nf,ks,lane): W1 -> 4096 threads, W2 -> 2048.
// Runs once per launch (~1 us); makes every GEMM block's B reads
// lane-contiguous dwordx4 from a 192KB L2-resident table. No LDS needed.
// ---------------------------------------------------------------------------
__global__ __launch_bounds__(256) void presplit_w_kernel(
    const float* __restrict__ W1, const float* __restrict__ W2,
    ushort* __restrict__ w1s, ushort* __restrict__ w2s)
{
    int tg = blockIdx.x * 256 + threadIdx.x;
    const float* W; ushort* out; int t;
    if (tg < 4096)      { W = W1; out = w1s; t = tg; }
    else if (tg < 6144) { W = W2; out = w2s; t = tg - 4096; }
    else return;

    int lane = t & 63;
    int ks   = (t >> 6) & 3;
    int nf   = (t >> 8) & 7;
    int kc   = t >> 11;            // 0..1 for W1, 0 for W2
    int k0   = kc * 128 + ks * 32 + (lane >> 4) * 8;
    int n    = nf * 16 + (lane & 15);

    frag_ab hi, lo;
    #pragma unroll
    for (int j = 0; j < 8; ++j) {
        ushort h, l;
        split2(W[(size_t)(k0 + j) * 128 + n], h, l);
        hi[j] = (short)h; lo[j] = (short)l;
    }
    size_t fbase = (size_t)((kc * 32 + nf * 4 + ks) * 2) * 64 + lane;
    ((frag_ab*)out)[fbase]      = hi;
    ((frag_ab*)out)[fbase + 64] = lo;
}

// ---------------------------------------------------------------------------
// K0..: CSR build chain (unchanged)
// ---------------------------------------------------------------------------
__global__ __launch_bounds__(256) void zero_kernel(int* __restrict__ p, int n) {
    int i = blockIdx.x * 256 + threadIdx.x;
    if (i < n) p[i] = 0;
}

__global__ __launch_bounds__(256) void hist_kernel(const int* __restrict__ ei,
                                                   int* __restrict__ deg) {
    int t = blockIdx.x * 256 + threadIdx.x;
    if (t < N_EDGES) atomicAdd(&deg[ei[N_EDGES + t]], 1);
}

__global__ __launch_bounds__(256) void block_sum_kernel(const int* __restrict__ deg,
                                                        int* __restrict__ bsum) {
    __shared__ int s[256];
    int i = blockIdx.x * 256 + threadIdx.x;
    s[threadIdx.x] = (i < N_NODES) ? deg[i] : 0;
    __syncthreads();
    #pragma unroll
    for (int o = 128; o > 0; o >>= 1) {
        if (threadIdx.x < o) s[threadIdx.x] += s[threadIdx.x + o];
        __syncthreads();
    }
    if (threadIdx.x == 0) bsum[blockIdx.x] = s[0];
}

__global__ __launch_bounds__(512) void scan_bsum_kernel(const int* __restrict__ bsum,
                                                        int* __restrict__ bpre,
                                                        int* __restrict__ offsets) {
    __shared__ int bufA[512], bufB[512];
    int t = threadIdx.x;
    int v = (t < NSCAN_BLOCKS) ? bsum[t] : 0;
    bufA[t] = v;
    __syncthreads();
    int* src = bufA; int* dst = bufB;
    #pragma unroll
    for (int o = 1; o < 512; o <<= 1) {
        dst[t] = src[t] + ((t >= o) ? src[t - o] : 0);
        __syncthreads();
        int* tmp = src; src = dst; dst = tmp;
    }
    if (t < NSCAN_BLOCKS) bpre[t] = src[t] - v;   // exclusive
    if (t == 0) offsets[N_NODES] = N_EDGES;
}

__global__ __launch_bounds__(256) void scan_block_kernel(const int* __restrict__ deg,
                                                         const int* __restrict__ bpre,
                                                         int* __restrict__ offsets) {
    __shared__ int bufA[256], bufB[256];
    int t = threadIdx.x;
    int i = blockIdx.x * 256 + t;
    int v = (i < N_NODES) ? deg[i] : 0;
    bufA[t] = v;
    __syncthreads();
    int* src = bufA; int* dst = bufB;
    #pragma unroll
    for (int o = 1; o < 256; o <<= 1) {
        dst[t] = src[t] + ((t >= o) ? src[t - o] : 0);
        __syncthreads();
        int* tmp = src; src = dst; dst = tmp;
    }
    if (i < N_NODES) offsets[i] = bpre[blockIdx.x] + src[t] - v;
}

__global__ __launch_bounds__(256) void csr_scatter_kernel(const int* __restrict__ ei,
                                                          const int* __restrict__ offsets,
                                                          int* __restrict__ cursor,
                                                          int* __restrict__ csr) {
    int t = blockIdx.x * 256 + threadIdx.x;
    if (t < N_EDGES) {
        int src = ei[t];
        int dst = ei[N_EDGES + t];
        int pos = atomicAdd(&cursor[dst], 1);
        csr[offsets[dst] + pos] = src;
    }
}

// ---------------------------------------------------------------------------
// K1: h = LN(LeakyReLU(x @ W1 + b1)) via 3-term bf16-split MFMA, LDS-FREE.
// Block 256 = 4 waves x 32 rows (BM=128). K=256 in two 128-chunks.
// A: direct-from-global fp32, split in-register. B: pre-tiled bf16 frags
// (w1s), lane-contiguous global loads, L1/L2-resident. No barriers.
// MFMA 16x16x32 bf16; C/D: col=lane&15, row=(lane>>4)*4+reg.
// ---------------------------------------------------------------------------
__global__ __launch_bounds__(256, 3) void gemm1_ln_mfma_kernel(
    const float* __restrict__ x, const ushort* __restrict__ w1s,
    const float* __restrict__ b1, const float* __restrict__ gamma,
    const float* __restrict__ beta, float* __restrict__ h)
{
    const int tid  = threadIdx.x;
    const int lane = tid & 63;
    const int wv   = tid >> 6;          // wave id 0..3
    const int r16  = lane & 15;
    const int g    = lane >> 4;         // 0..3
    const int row0 = blockIdx.x * 128;

    const frag_ab* B1 = (const frag_ab*)w1s;

    f32x4 acc[2][8];
    #pragma unroll
    for (int mf = 0; mf < 2; ++mf)
        #pragma unroll
        for (int nf = 0; nf < 8; ++nf)
            acc[mf][nf] = (f32x4){0.f, 0.f, 0.f, 0.f};

    // per-lane epilogue params (cols nf*16 + r16)
    float b1v[8], gv[8], bv[8];
    #pragma unroll
    for (int nf = 0; nf < 8; ++nf) {
        int cidx = nf * 16 + r16;
        b1v[nf] = b1[cidx]; gv[nf] = gamma[cidx]; bv[nf] = beta[cidx];
    }

    #pragma unroll
    for (int kc = 0; kc < 2; ++kc) {
        // prefetch this chunk's A rows (raw fp32) — 16 x dwordx4 per lane
        float4 araw[2][4][2];
        #pragma unroll
        for (int mf = 0; mf < 2; ++mf) {
            int r_a = row0 + wv * 32 + mf * 16 + r16;
            r_a = (r_a < N_NODES) ? r_a : (N_NODES - 1);
            const float* xp = x + (size_t)r_a * C_IN + kc * 128 + g * 8;
            #pragma unroll
            for (int ks = 0; ks < 4; ++ks) {
                araw[mf][ks][0] = *(const float4*)(xp + ks * 32);
                araw[mf][ks][1] = *(const float4*)(xp + ks * 32 + 4);
            }
        }

        #pragma unroll
        for (int ks = 0; ks < 4; ++ks) {
            frag_ab aHi[2], aLo[2];
            split8(araw[0][ks][0], araw[0][ks][1], aHi[0], aLo[0]);
            split8(araw[1][ks][0], araw[1][ks][1], aHi[1], aLo[1]);
            const int fb = (kc * 32 + ks) * 128 + lane;   // + nf*4*128
            #pragma unroll
            for (int nf = 0; nf < 8; ++nf) {
                frag_ab bHi = B1[fb + nf * 512];
                frag_ab bLo = B1[fb + nf * 512 + 64];
                acc[0][nf] = __builtin_amdgcn_mfma_f32_16x16x32_bf16(aHi[0], bHi, acc[0][nf], 0, 0, 0);
                acc[0][nf] = __builtin_amdgcn_mfma_f32_16x16x32_bf16(aLo[0], bHi, acc[0][nf], 0, 0, 0);
                acc[0][nf] = __builtin_amdgcn_mfma_f32_16x16x32_bf16(aHi[0], bLo, acc[0][nf], 0, 0, 0);
                acc[1][nf] = __builtin_amdgcn_mfma_f32_16x16x32_bf16(aHi[1], bHi, acc[1][nf], 0, 0, 0);
                acc[1][nf] = __builtin_amdgcn_mfma_f32_16x16x32_bf16(aLo[1], bHi, acc[1][nf], 0, 0, 0);
                acc[1][nf] = __builtin_amdgcn_mfma_f32_16x16x32_bf16(aHi[1], bLo, acc[1][nf], 0, 0, 0);
            }
        }
    }

    // ---- epilogue: +b1, LeakyReLU, LayerNorm, store h ----
    #pragma unroll
    for (int mf = 0; mf < 2; ++mf)
        #pragma unroll
        for (int nf = 0; nf < 8; ++nf)
            #pragma unroll
            for (int rg = 0; rg < 4; ++rg) {
                float v = acc[mf][nf][rg] + b1v[nf];
                acc[mf][nf][rg] = (v > 0.f) ? v : NEG_SLOPE * v;
            }

    #pragma unroll
    for (int mf = 0; mf < 2; ++mf) {
        #pragma unroll
        for (int rg = 0; rg < 4; ++rg) {
            float s = 0.f, ss = 0.f;
            #pragma unroll
            for (int nf = 0; nf < 8; ++nf) {
                float v = acc[mf][nf][rg];
                s += v; ss += v * v;
            }
            // reduce across the 16 lanes holding this row (low-4 lane bits)
            #pragma unroll
            for (int m = 1; m < 16; m <<= 1) {
                s  += __shfl_xor(s,  m, 64);
                ss += __shfl_xor(ss, m, 64);
            }
            float mu   = s * (1.f / C_HID);
            float var  = ss * (1.f / C_HID) - mu * mu;
            float rstd = rsqrtf(var + LN_EPS);
            int row = row0 + wv * 32 + mf * 16 + (g << 2) + rg;
            if (row < N_NODES) {
                #pragma unroll
                for (int nf = 0; nf < 8; ++nf) {
                    float o = (acc[mf][nf][rg] - mu) * rstd * gv[nf] + bv[nf];
                    h[(size_t)row * C_HID + nf * 16 + r16] = o;
                }
            }
        }
    }
}

// ---------------------------------------------------------------------------
// K2: gather-min, one wave per node (unchanged).
// ---------------------------------------------------------------------------
__global__ __launch_bounds__(256) void gather_min_kernel(
    const float* __restrict__ h, const int* __restrict__ offsets,
    const int* __restrict__ csr, float* __restrict__ agg)
{
    const int lane = threadIdx.x & 63;
    const int row  = blockIdx.x * 4 + (threadIdx.x >> 6);
    if (row >= N_NODES) return;

    const int beg = offsets[row];
    const int end = offsets[row + 1];

    float m0 = INFINITY, m1 = INFINITY;

    for (int j0 = beg; j0 < end; j0 += 64) {
        const int cnt = min(64, end - j0);
        int idx = (lane < cnt) ? csr[j0 + lane] : 0;
        for (int k = 0; k < cnt; k += 4) {
            int s0 = __shfl(idx, k + 0);
            int s1 = __shfl(idx, k + 1);
            int s2 = __shfl(idx, k + 2);
            int s3 = __shfl(idx, k + 3);
            float2 v0 = ((const float2*)(h + (size_t)s0 * C_HID))[lane];
            float2 v1 = make_float2(INFINITY, INFINITY);
            float2 v2 = make_float2(INFINITY, INFINITY);
            float2 v3 = make_float2(INFINITY, INFINITY);
            if (k + 1 < cnt) v1 = ((const float2*)(h + (size_t)s1 * C_HID))[lane];
            if (k + 2 < cnt) v2 = ((const float2*)(h + (size_t)s2 * C_HID))[lane];
            if (k + 3 < cnt) v3 = ((const float2*)(h + (size_t)s3 * C_HID))[lane];
            m0 = fminf(fminf(m0, v0.x), fminf(fminf(v1.x, v2.x), v3.x));
            m1 = fminf(fminf(m1, v0.y), fminf(fminf(v1.y, v2.y), v3.y));
        }
    }

    if (m0 == INFINITY) m0 = 0.f;   // empty segment -> 0 (PyG fill; h is finite)
    if (m1 == INFINITY) m1 = 0.f;
    ((float2*)(agg + (size_t)row * C_HID))[lane] = make_float2(m0, m1);
}

// ---------------------------------------------------------------------------
// K3: out = agg @ W2 + b2 via 3-term bf16-split MFMA, LDS-FREE (K=128).
// ---------------------------------------------------------------------------
__global__ __launch_bounds__(256, 3) void gemm2_mfma_kernel(
    const float* __restrict__ agg, const ushort* __restrict__ w2s,
    const float* __restrict__ b2, float* __restrict__ out)
{
    const int tid  = threadIdx.x;
    const int lane = tid & 63;
    const int wv   = tid >> 6;
    const int r16  = lane & 15;
    const int g    = lane >> 4;
    const int row0 = blockIdx.x * 128;

    const frag_ab* B2 = (const frag_ab*)w2s;

    f32x4 acc[2][8];
    #pragma unroll
    for (int mf = 0; mf < 2; ++mf)
        #pragma unroll
        for (int nf = 0; nf < 8; ++nf)
            acc[mf][nf] = (f32x4){0.f, 0.f, 0.f, 0.f};

    float b2v[8];
    #pragma unroll
    for (int nf = 0; nf < 8; ++nf) b2v[nf] = b2[nf * 16 + r16];

    // prefetch A (agg rows, K=128)
    float4 araw[2][4][2];
    #pragma unroll
    for (int mf = 0; mf < 2; ++mf) {
        int r_a = row0 + wv * 32 + mf * 16 + r16;
        r_a = (r_a < N_NODES) ? r_a : (N_NODES - 1);
        const float* ap = agg + (size_t)r_a * C_HID + g * 8;
        #pragma unroll
        for (int ks = 0; ks < 4; ++ks) {
            araw[mf][ks][0] = *(const float4*)(ap + ks * 32);
            araw[mf][ks][1] = *(const float4*)(ap + ks * 32 + 4);
        }
    }

    #pragma unroll
    for (int ks = 0; ks < 4; ++ks) {
        frag_ab aHi[2], aLo[2];
        split8(araw[0][ks][0], araw[0][ks][1], aHi[0], aLo[0]);
        split8(araw[1][ks][0], araw[1][ks][1], aHi[1], aLo[1]);
        const int fb = ks * 128 + lane;   // + nf*4*128
        #pragma unroll
        for (int nf = 0; nf < 8; ++nf) {
            frag_ab bHi = B2[fb + nf * 512];
            frag_ab bLo = B2[fb + nf * 512 + 64];
            acc[0][nf] = __builtin_amdgcn_mfma_f32_16x16x32_bf16(aHi[0], bHi, acc[0][nf], 0, 0, 0);
            acc[0][nf] = __builtin_amdgcn_mfma_f32_16x16x32_bf16(aLo[0], bHi, acc[0][nf], 0, 0, 0);
            acc[0][nf] = __builtin_amdgcn_mfma_f32_16x16x32_bf16(aHi[0], bLo, acc[0][nf], 0, 0, 0);
            acc[1][nf] = __builtin_amdgcn_mfma_f32_16x16x32_bf16(aHi[1], bHi, acc[1][nf], 0, 0, 0);
            acc[1][nf] = __builtin_amdgcn_mfma_f32_16x16x32_bf16(aLo[1], bHi, acc[1][nf], 0, 0, 0);
            acc[1][nf] = __builtin_amdgcn_mfma_f32_16x16x32_bf16(aHi[1], bLo, acc[1][nf], 0, 0, 0);
        }
    }

    #pragma unroll
    for (int mf = 0; mf < 2; ++mf) {
        #pragma unroll
        for (int rg = 0; rg < 4; ++rg) {
            int row = row0 + wv * 32 + mf * 16 + (g << 2) + rg;
            if (row < N_NODES) {
                #pragma unroll
                for (int nf = 0; nf < 8; ++nf)
                    out[(size_t)row * C_OUT + nf * 16 + r16] = acc[mf][nf][rg] + b2v[nf];
            }
        }
    }
}

// ---------------------------------------------------------------------------
extern "C" void kernel_launch(void* const* d_in, const int* in_sizes, int n_in,
                              void* d_out, int out_size, void* d_ws, size_t ws_size,
                              hipStream_t stream)
{
    const float* x     = (const float*)d_in[0];
    const int*   ei    = (const int*)d_in[3];   // [2, E] row-major int32
    const float* W1    = (const float*)d_in[4];
    const float* b1    = (const float*)d_in[5];
    const float* gamma = (const float*)d_in[6];
    const float* beta  = (const float*)d_in[7];
    const float* W2    = (const float*)d_in[8];
    const float* b2    = (const float*)d_in[9];
    float*       out   = (float*)d_out;

    // ws: h 51.2MB | agg 51.2MB | deg | cursor | offsets | bsum | bpre | csr | w1s 128KB | w2s 64KB
    char* p = (char*)d_ws;
    float*  h       = (float*)p;           p += (size_t)N_NODES * C_HID * 4;
    float*  agg     = (float*)p;           p += (size_t)N_NODES * C_HID * 4;
    int*    deg     = (int*)p;             p += 400000;
    int*    cursor  = (int*)p;             p += 400000;
    int*    offsets = (int*)p;             p += 400016;   // 100001 ints, padded
    int*    bsum    = (int*)p;             p += 1600;
    int*    bpre    = (int*)p;             p += 1600;
    int*    csr     = (int*)p;             p += (size_t)N_EDGES * 4;
    ushort* w1s     = (ushort*)p;          p += 131072;
    ushort* w2s     = (ushort*)p;

    const int grid_e    = (N_EDGES + 255) / 256;   // 2344
    const int grid_gemm = (N_NODES + 127) / 128;   // 782

    presplit_w_kernel<<<24, 256, 0, stream>>>(W1, W2, w1s, w2s);
    zero_kernel<<<(2 * N_NODES + 255) / 256, 256, 0, stream>>>(deg, 2 * N_NODES);
    hist_kernel<<<grid_e, 256, 0, stream>>>(ei, deg);
    block_sum_kernel<<<NSCAN_BLOCKS, 256, 0, stream>>>(deg, bsum);
    scan_bsum_kernel<<<1, 512, 0, stream>>>(bsum, bpre, offsets);
    scan_block_kernel<<<NSCAN_BLOCKS, 256, 0, stream>>>(deg, bpre, offsets);
    csr_scatter_kernel<<<grid_e, 256, 0, stream>>>(ei, offsets, cursor, csr);
    gemm1_ln_mfma_kernel<<<grid_gemm, 256, 0, stream>>>(x, w1s, b1, gamma, beta, h);
    gather_min_kernel<<<(N_NODES + 3) / 4, 256, 0, stream>>>(h, offsets, csr, agg);
    gemm2_mfma_kernel<<<grid_gemm, 256, 0, stream>>>(agg, w2s, b2, out);
}

// Round 7
// 342.312 us; speedup vs baseline: 1.1293x; 1.1293x over previous
//
#include <hip/hip_runtime.h>
#include <hip/hip_bf16.h>
#include <cstdint>

#define N_NODES 100000
#define N_EDGES 600000
#define C_IN    256
#define C_HID   128
#define C_OUT   128
#define LN_EPS  1e-5f
#define NEG_SLOPE 0.01f

#define NSCAN_BLOCKS 391  // ceil(100000/256)

typedef float f32x4 __attribute__((ext_vector_type(4)));
typedef __attribute__((ext_vector_type(8))) short frag_ab;  // 8 bf16 in 4 VGPRs

// ---- fp32 -> bf16 hi/lo split (RTZ hi, residual in lo; ~2^-16 rel total) ----
__device__ __forceinline__ void split2(float f, ushort& h, ushort& l) {
    unsigned u = __float_as_uint(f);
    h = (ushort)(u >> 16);
    float d = f - __uint_as_float(u & 0xFFFF0000u);
    l = (ushort)(__float_as_uint(d) >> 16);
}

__device__ __forceinline__ void split8(const float4& p, const float4& q,
                                       frag_ab& hi, frag_ab& lo) {
    ushort h, l;
    split2(p.x, h, l); hi[0] = (short)h; lo[0] = (short)l;
    split2(p.y, h, l); hi[1] = (short)h; lo[1] = (short)l;
    split2(p.z, h, l); hi[2] = (short)h; lo[2] = (short)l;
    split2(p.w, h, l); hi[3] = (short)h; lo[3] = (short)l;
    split2(q.x, h, l); hi[4] = (short)h; lo[4] = (short)l;
    split2(q.y, h, l); hi[5] = (short)h; lo[5] = (short)l;
    split2(q.z, h, l); hi[6] = (short)h; lo[6] = (short)l;
    split2(q.w, h, l); hi[7] = (short)h; lo[7] = (short)l;
}

// async global->LDS, 16B per lane. LDS dst is wave-uniform base; HW adds lane*16.
__device__ __forceinline__ void gload_lds16(const void* g, void* l) {
    __builtin_amdgcn_global_load_lds(
        (const __attribute__((address_space(1))) unsigned int*)g,
        (__attribute__((address_space(3))) unsigned int*)l, 16, 0, 0);
}

// ---------------------------------------------------------------------------
// K_setup: zero deg+cursor (200000 ints) AND pre-split W1/W2 into bf16 hi/lo
// frag table, GROUP-MAJOR order:
//   group g = kc*4+ks (16KB each: 8 nf x {hi,lo} x 64 lanes x 16B)
//   frag_ab index = (g*16 + nf*2 + plane)*64 + lane
//   value(lane,j) = W[k = kc*128+ks*32+(lane>>4)*8+j][n = nf*16+(lane&15)]
// This layout is lane-contiguous -> global_load_lds-compatible, ds-conflict-free.
// ---------------------------------------------------------------------------
__global__ __launch_bounds__(256) void setup_kernel(
    const float* __restrict__ W1, const float* __restrict__ W2,
    ushort* __restrict__ w1s, ushort* __restrict__ w2s, int* __restrict__ dz)
{
    int tg = blockIdx.x * 256 + threadIdx.x;
    if (tg < 2 * N_NODES) dz[tg] = 0;   // deg | cursor (contiguous)

    const float* W; ushort* out; int t;
    if (tg < 4096)      { W = W1; out = w1s; t = tg; }
    else if (tg < 6144) { W = W2; out = w2s; t = tg - 4096; }
    else return;

    int lane = t & 63;
    int ks   = (t >> 6) & 3;
    int nf   = (t >> 8) & 7;
    int kc   = t >> 11;            // 0..1 for W1, 0 for W2
    int k0   = kc * 128 + ks * 32 + (lane >> 4) * 8;
    int n    = nf * 16 + (lane & 15);

    frag_ab hi, lo;
    #pragma unroll
    for (int j = 0; j < 8; ++j) {
        ushort h, l;
        split2(W[(size_t)(k0 + j) * 128 + n], h, l);
        hi[j] = (short)h; lo[j] = (short)l;
    }
    size_t fi = ((size_t)(kc * 4 + ks) * 16 + nf * 2) * 64 + lane;
    ((frag_ab*)out)[fi]      = hi;
    ((frag_ab*)out)[fi + 64] = lo;
}

// ---------------------------------------------------------------------------
// CSR build chain
// ---------------------------------------------------------------------------
__global__ __launch_bounds__(256) void hist_kernel(const int* __restrict__ ei,
                                                   int* __restrict__ deg) {
    int t = blockIdx.x * 256 + threadIdx.x;
    if (t < N_EDGES) atomicAdd(&deg[ei[N_EDGES + t]], 1);
}

__global__ __launch_bounds__(256) void block_sum_kernel(const int* __restrict__ deg,
                                                        int* __restrict__ bsum) {
    __shared__ int s[256];
    int i = blockIdx.x * 256 + threadIdx.x;
    s[threadIdx.x] = (i < N_NODES) ? deg[i] : 0;
    __syncthreads();
    #pragma unroll
    for (int o = 128; o > 0; o >>= 1) {
        if (threadIdx.x < o) s[threadIdx.x] += s[threadIdx.x + o];
        __syncthreads();
    }
    if (threadIdx.x == 0) bsum[blockIdx.x] = s[0];
}

__global__ __launch_bounds__(512) void scan_bsum_kernel(const int* __restrict__ bsum,
                                                        int* __restrict__ bpre,
                                                        int* __restrict__ offsets) {
    __shared__ int bufA[512], bufB[512];
    int t = threadIdx.x;
    int v = (t < NSCAN_BLOCKS) ? bsum[t] : 0;
    bufA[t] = v;
    __syncthreads();
    int* src = bufA; int* dst = bufB;
    #pragma unroll
    for (int o = 1; o < 512; o <<= 1) {
        dst[t] = src[t] + ((t >= o) ? src[t - o] : 0);
        __syncthreads();
        int* tmp = src; src = dst; dst = tmp;
    }
    if (t < NSCAN_BLOCKS) bpre[t] = src[t] - v;   // exclusive
    if (t == 0) offsets[N_NODES] = N_EDGES;
}

__global__ __launch_bounds__(256) void scan_block_kernel(const int* __restrict__ deg,
                                                         const int* __restrict__ bpre,
                                                         int* __restrict__ offsets) {
    __shared__ int bufA[256], bufB[256];
    int t = threadIdx.x;
    int i = blockIdx.x * 256 + t;
    int v = (i < N_NODES) ? deg[i] : 0;
    bufA[t] = v;
    __syncthreads();
    int* src = bufA; int* dst = bufB;
    #pragma unroll
    for (int o = 1; o < 256; o <<= 1) {
        dst[t] = src[t] + ((t >= o) ? src[t - o] : 0);
        __syncthreads();
        int* tmp = src; src = dst; dst = tmp;
    }
    if (i < N_NODES) offsets[i] = bpre[blockIdx.x] + src[t] - v;
}

__global__ __launch_bounds__(256) void csr_scatter_kernel(const int* __restrict__ ei,
                                                          const int* __restrict__ offsets,
                                                          int* __restrict__ cursor,
                                                          int* __restrict__ csr) {
    int t = blockIdx.x * 256 + threadIdx.x;
    if (t < N_EDGES) {
        int src = ei[t];
        int dst = ei[N_EDGES + t];
        int pos = atomicAdd(&cursor[dst], 1);
        csr[offsets[dst] + pos] = src;
    }
}

// ---------------------------------------------------------------------------
// K1: h = LN(LeakyReLU(x @ W1 + b1)) via 3-term bf16-split MFMA.
// 2-phase pipeline: per 16KB K-group, issue {next A (4 dwordx4) + next B stage
// (4 global_load_lds)} -> s_waitcnt vmcnt(8) (counted, never drained) ->
// raw s_barrier -> 16 ds_read_b128 + 48 MFMA -> s_barrier.
// LDS 2x16KB double buffer. Block 256 = 4 waves x 32 rows (BM=128).
// ---------------------------------------------------------------------------
__global__ __launch_bounds__(256, 3) void gemm1_ln_mfma_kernel(
    const float* __restrict__ x, const ushort* __restrict__ w1s,
    const float* __restrict__ b1, const float* __restrict__ gamma,
    const float* __restrict__ beta, float* __restrict__ h)
{
    __shared__ ushort sB[2][8192];   // 2 x 16KB

    const int tid  = threadIdx.x;
    const int lane = tid & 63;
    const int wv   = tid >> 6;          // wave id 0..3
    const int r16  = lane & 15;
    const int quad = lane >> 4;         // 0..3
    const int row0 = blockIdx.x * 128;

    int rA[2];
    const float* xrow[2];
    #pragma unroll
    for (int mf = 0; mf < 2; ++mf) {
        int r = row0 + wv * 32 + mf * 16 + r16;
        rA[mf] = (r < N_NODES) ? r : (N_NODES - 1);
        xrow[mf] = x + (size_t)rA[mf] * C_IN;
    }

    f32x4 acc[2][8];
    #pragma unroll
    for (int mf = 0; mf < 2; ++mf)
        #pragma unroll
        for (int nf = 0; nf < 8; ++nf)
            acc[mf][nf] = (f32x4){0.f, 0.f, 0.f, 0.f};

    float4 a[2][2][2];   // [parity][mf][half]

    auto ISSUE = [&](int g) {
        const int par = g & 1;
        const int col0 = (g >> 2) * 128 + (g & 3) * 32 + quad * 8;
        #pragma unroll
        for (int mf = 0; mf < 2; ++mf) {
            const float* xp = xrow[mf] + col0;
            a[par][mf][0] = *(const float4*)(xp);
            a[par][mf][1] = *(const float4*)(xp + 4);
        }
        const char* gsrc = (const char*)w1s + g * 16384 + wv * 4096 + lane * 16;
        char* ldst = (char*)&sB[par][0] + wv * 4096;
        #pragma unroll
        for (int it = 0; it < 4; ++it)
            gload_lds16(gsrc + it * 1024, ldst + it * 1024);
    };

    ISSUE(0);
    #pragma unroll
    for (int g = 0; g < 8; ++g) {
        if (g < 7) {
            ISSUE(g + 1);
            asm volatile("s_waitcnt vmcnt(8)" ::: "memory");
        } else {
            asm volatile("s_waitcnt vmcnt(0)" ::: "memory");
        }
        __builtin_amdgcn_s_barrier();
        __builtin_amdgcn_sched_barrier(0);

        const int par = g & 1;
        frag_ab aHi[2], aLo[2];
        split8(a[par][0][0], a[par][0][1], aHi[0], aLo[0]);
        split8(a[par][1][0], a[par][1][1], aHi[1], aLo[1]);
        const char* bb = (const char*)&sB[par][0] + lane * 16;
        #pragma unroll
        for (int nf = 0; nf < 8; ++nf) {
            frag_ab bHi = *(const frag_ab*)(bb + nf * 2048);
            frag_ab bLo = *(const frag_ab*)(bb + nf * 2048 + 1024);
            acc[0][nf] = __builtin_amdgcn_mfma_f32_16x16x32_bf16(aHi[0], bHi, acc[0][nf], 0, 0, 0);
            acc[0][nf] = __builtin_amdgcn_mfma_f32_16x16x32_bf16(aLo[0], bHi, acc[0][nf], 0, 0, 0);
            acc[0][nf] = __builtin_amdgcn_mfma_f32_16x16x32_bf16(aHi[0], bLo, acc[0][nf], 0, 0, 0);
            acc[1][nf] = __builtin_amdgcn_mfma_f32_16x16x32_bf16(aHi[1], bHi, acc[1][nf], 0, 0, 0);
            acc[1][nf] = __builtin_amdgcn_mfma_f32_16x16x32_bf16(aLo[1], bHi, acc[1][nf], 0, 0, 0);
            acc[1][nf] = __builtin_amdgcn_mfma_f32_16x16x32_bf16(aHi[1], bLo, acc[1][nf], 0, 0, 0);
        }
        __builtin_amdgcn_sched_barrier(0);
        __builtin_amdgcn_s_barrier();
    }

    // ---- epilogue: +b1, LeakyReLU, LayerNorm, store h ----
    float b1v[8], gv[8], bv[8];
    #pragma unroll
    for (int nf = 0; nf < 8; ++nf) {
        int cidx = nf * 16 + r16;
        b1v[nf] = b1[cidx]; gv[nf] = gamma[cidx]; bv[nf] = beta[cidx];
    }

    #pragma unroll
    for (int mf = 0; mf < 2; ++mf)
        #pragma unroll
        for (int nf = 0; nf < 8; ++nf)
            #pragma unroll
            for (int rg = 0; rg < 4; ++rg) {
                float v = acc[mf][nf][rg] + b1v[nf];
                acc[mf][nf][rg] = (v > 0.f) ? v : NEG_SLOPE * v;
            }

    #pragma unroll
    for (int mf = 0; mf < 2; ++mf) {
        #pragma unroll
        for (int rg = 0; rg < 4; ++rg) {
            float s = 0.f, ss = 0.f;
            #pragma unroll
            for (int nf = 0; nf < 8; ++nf) {
                float v = acc[mf][nf][rg];
                s += v; ss += v * v;
            }
            #pragma unroll
            for (int m = 1; m < 16; m <<= 1) {
                s  += __shfl_xor(s,  m, 64);
                ss += __shfl_xor(ss, m, 64);
            }
            float mu   = s * (1.f / C_HID);
            float var  = ss * (1.f / C_HID) - mu * mu;
            float rstd = rsqrtf(var + LN_EPS);
            int row = row0 + wv * 32 + mf * 16 + (quad << 2) + rg;
            if (row < N_NODES) {
                #pragma unroll
                for (int nf = 0; nf < 8; ++nf) {
                    float o = (acc[mf][nf][rg] - mu) * rstd * gv[nf] + bv[nf];
                    h[(size_t)row * C_HID + nf * 16 + r16] = o;
                }
            }
        }
    }
}

// ---------------------------------------------------------------------------
// K2: gather-min, one wave per node (unchanged).
// ---------------------------------------------------------------------------
__global__ __launch_bounds__(256) void gather_min_kernel(
    const float* __restrict__ h, const int* __restrict__ offsets,
    const int* __restrict__ csr, float* __restrict__ agg)
{
    const int lane = threadIdx.x & 63;
    const int row  = blockIdx.x * 4 + (threadIdx.x >> 6);
    if (row >= N_NODES) return;

    const int beg = offsets[row];
    const int end = offsets[row + 1];

    float m0 = INFINITY, m1 = INFINITY;

    for (int j0 = beg; j0 < end; j0 += 64) {
        const int cnt = min(64, end - j0);
        int idx = (lane < cnt) ? csr[j0 + lane] : 0;
        for (int k = 0; k < cnt; k += 4) {
            int s0 = __shfl(idx, k + 0);
            int s1 = __shfl(idx, k + 1);
            int s2 = __shfl(idx, k + 2);
            int s3 = __shfl(idx, k + 3);
            float2 v0 = ((const float2*)(h + (size_t)s0 * C_HID))[lane];
            float2 v1 = make_float2(INFINITY, INFINITY);
            float2 v2 = make_float2(INFINITY, INFINITY);
            float2 v3 = make_float2(INFINITY, INFINITY);
            if (k + 1 < cnt) v1 = ((const float2*)(h + (size_t)s1 * C_HID))[lane];
            if (k + 2 < cnt) v2 = ((const float2*)(h + (size_t)s2 * C_HID))[lane];
            if (k + 3 < cnt) v3 = ((const float2*)(h + (size_t)s3 * C_HID))[lane];
            m0 = fminf(fminf(m0, v0.x), fminf(fminf(v1.x, v2.x), v3.x));
            m1 = fminf(fminf(m1, v0.y), fminf(fminf(v1.y, v2.y), v3.y));
        }
    }

    if (m0 == INFINITY) m0 = 0.f;   // empty segment -> 0 (PyG fill; h is finite)
    if (m1 == INFINITY) m1 = 0.f;
    ((float2*)(agg + (size_t)row * C_HID))[lane] = make_float2(m0, m1);
}

// ---------------------------------------------------------------------------
// K3: out = agg @ W2 + b2 via 3-term bf16-split MFMA, same 2-phase pipeline
// (4 K-groups).
// ---------------------------------------------------------------------------
__global__ __launch_bounds__(256, 3) void gemm2_mfma_kernel(
    const float* __restrict__ agg, const ushort* __restrict__ w2s,
    const float* __restrict__ b2, float* __restrict__ out)
{
    __shared__ ushort sB[2][8192];

    const int tid  = threadIdx.x;
    const int lane = tid & 63;
    const int wv   = tid >> 6;
    const int r16  = lane & 15;
    const int quad = lane >> 4;
    const int row0 = blockIdx.x * 128;

    const float* arow[2];
    #pragma unroll
    for (int mf = 0; mf < 2; ++mf) {
        int r = row0 + wv * 32 + mf * 16 + r16;
        r = (r < N_NODES) ? r : (N_NODES - 1);
        arow[mf] = agg + (size_t)r * C_HID;
    }

    f32x4 acc[2][8];
    #pragma unroll
    for (int mf = 0; mf < 2; ++mf)
        #pragma unroll
        for (int nf = 0; nf < 8; ++nf)
            acc[mf][nf] = (f32x4){0.f, 0.f, 0.f, 0.f};

    float4 a[2][2][2];

    auto ISSUE = [&](int g) {
        const int par = g & 1;
        const int col0 = g * 32 + quad * 8;
        #pragma unroll
        for (int mf = 0; mf < 2; ++mf) {
            const float* ap = arow[mf] + col0;
            a[par][mf][0] = *(const float4*)(ap);
            a[par][mf][1] = *(const float4*)(ap + 4);
        }
        const char* gsrc = (const char*)w2s + g * 16384 + wv * 4096 + lane * 16;
        char* ldst = (char*)&sB[par][0] + wv * 4096;
        #pragma unroll
        for (int it = 0; it < 4; ++it)
            gload_lds16(gsrc + it * 1024, ldst + it * 1024);
    };

    ISSUE(0);
    #pragma unroll
    for (int g = 0; g < 4; ++g) {
        if (g < 3) {
            ISSUE(g + 1);
            asm volatile("s_waitcnt vmcnt(8)" ::: "memory");
        } else {
            asm volatile("s_waitcnt vmcnt(0)" ::: "memory");
        }
        __builtin_amdgcn_s_barrier();
        __builtin_amdgcn_sched_barrier(0);

        const int par = g & 1;
        frag_ab aHi[2], aLo[2];
        split8(a[par][0][0], a[par][0][1], aHi[0], aLo[0]);
        split8(a[par][1][0], a[par][1][1], aHi[1], aLo[1]);
        const char* bb = (const char*)&sB[par][0] + lane * 16;
        #pragma unroll
        for (int nf = 0; nf < 8; ++nf) {
            frag_ab bHi = *(const frag_ab*)(bb + nf * 2048);
            frag_ab bLo = *(const frag_ab*)(bb + nf * 2048 + 1024);
            acc[0][nf] = __builtin_amdgcn_mfma_f32_16x16x32_bf16(aHi[0], bHi, acc[0][nf], 0, 0, 0);
            acc[0][nf] = __builtin_amdgcn_mfma_f32_16x16x32_bf16(aLo[0], bHi, acc[0][nf], 0, 0, 0);
            acc[0][nf] = __builtin_amdgcn_mfma_f32_16x16x32_bf16(aHi[0], bLo, acc[0][nf], 0, 0, 0);
            acc[1][nf] = __builtin_amdgcn_mfma_f32_16x16x32_bf16(aHi[1], bHi, acc[1][nf], 0, 0, 0);
            acc[1][nf] = __builtin_amdgcn_mfma_f32_16x16x32_bf16(aLo[1], bHi, acc[1][nf], 0, 0, 0);
            acc[1][nf] = __builtin_amdgcn_mfma_f32_16x16x32_bf16(aHi[1], bLo, acc[1][nf], 0, 0, 0);
        }
        __builtin_amdgcn_sched_barrier(0);
        __builtin_amdgcn_s_barrier();
    }

    float b2v[8];
    #pragma unroll
    for (int nf = 0; nf < 8; ++nf) b2v[nf] = b2[nf * 16 + r16];

    #pragma unroll
    for (int mf = 0; mf < 2; ++mf) {
        #pragma unroll
        for (int rg = 0; rg < 4; ++rg) {
            int row = row0 + wv * 32 + mf * 16 + (quad << 2) + rg;
            if (row < N_NODES) {
                #pragma unroll
                for (int nf = 0; nf < 8; ++nf)
                    out[(size_t)row * C_OUT + nf * 16 + r16] = acc[mf][nf][rg] + b2v[nf];
            }
        }
    }
}

// ---------------------------------------------------------------------------
extern "C" void kernel_launch(void* const* d_in, const int* in_sizes, int n_in,
                              void* d_out, int out_size, void* d_ws, size_t ws_size,
                              hipStream_t stream)
{
    const float* x     = (const float*)d_in[0];
    const int*   ei    = (const int*)d_in[3];   // [2, E] row-major int32
    const float* W1    = (const float*)d_in[4];
    const float* b1    = (const float*)d_in[5];
    const float* gamma = (const float*)d_in[6];
    const float* beta  = (const float*)d_in[7];
    const float* W2    = (const float*)d_in[8];
    const float* b2    = (const float*)d_in[9];
    float*       out   = (float*)d_out;

    // ws: h 51.2MB | agg 51.2MB | deg | cursor | offsets | bsum | bpre | csr | w1s 128KB | w2s 64KB
    char* p = (char*)d_ws;
    float*  h       = (float*)p;           p += (size_t)N_NODES * C_HID * 4;
    float*  agg     = (float*)p;           p += (size_t)N_NODES * C_HID * 4;
    int*    deg     = (int*)p;             p += 400000;   // cursor follows contiguously
    int*    cursor  = (int*)p;             p += 400000;
    int*    offsets = (int*)p;             p += 400016;   // 100001 ints, padded
    int*    bsum    = (int*)p;             p += 1600;
    int*    bpre    = (int*)p;             p += 1600;
    int*    csr     = (int*)p;             p += (size_t)N_EDGES * 4;
    ushort* w1s     = (ushort*)p;          p += 131072;
    ushort* w2s     = (ushort*)p;

    const int grid_e    = (N_EDGES + 255) / 256;   // 2344
    const int grid_gemm = (N_NODES + 127) / 128;   // 782

    setup_kernel<<<grid_gemm, 256, 0, stream>>>(W1, W2, w1s, w2s, deg);
    hist_kernel<<<grid_e, 256, 0, stream>>>(ei, deg);
    block_sum_kernel<<<NSCAN_BLOCKS, 256, 0, stream>>>(deg, bsum);
    scan_bsum_kernel<<<1, 512, 0, stream>>>(bsum, bpre, offsets);
    scan_block_kernel<<<NSCAN_BLOCKS, 256, 0, stream>>>(deg, bpre, offsets);
    csr_scatter_kernel<<<grid_e, 256, 0, stream>>>(ei, offsets, cursor, csr);
    gemm1_ln_mfma_kernel<<<grid_gemm, 256, 0, stream>>>(x, w1s, b1, gamma, beta, h);
    gather_min_kernel<<<(N_NODES + 3) / 4, 256, 0, stream>>>(h, offsets, csr, agg);
    gemm2_mfma_kernel<<<grid_gemm, 256, 0, stream>>>(agg, w2s, b2, out);
}

// Round 8
// 335.622 us; speedup vs baseline: 1.1518x; 1.0199x over previous
//
#include <hip/hip_runtime.h>
#include <hip/hip_bf16.h>
#include <cstdint>

#define N_NODES 100000
#define N_EDGES 600000
#define C_IN    256
#define C_HID   128
#define C_OUT   128
#define LN_EPS  1e-5f
#define NEG_SLOPE 0.01f

#define NSCAN_BLOCKS 391  // ceil(100000/256)

typedef float f32x4 __attribute__((ext_vector_type(4)));
typedef __attribute__((ext_vector_type(8))) short frag_ab;  // 8 bf16 in 4 VGPRs

#define WAITV(N) asm volatile("s_waitcnt vmcnt(" #N ")" ::: "memory")

// ---- fp32 -> bf16 hi/lo split (RTZ hi, residual in lo; ~2^-16 rel total) ----
__device__ __forceinline__ void split2(float f, ushort& h, ushort& l) {
    unsigned u = __float_as_uint(f);
    h = (ushort)(u >> 16);
    float d = f - __uint_as_float(u & 0xFFFF0000u);
    l = (ushort)(__float_as_uint(d) >> 16);
}

__device__ __forceinline__ void split8(const float4& p, const float4& q,
                                       frag_ab& hi, frag_ab& lo) {
    ushort h, l;
    split2(p.x, h, l); hi[0] = (short)h; lo[0] = (short)l;
    split2(p.y, h, l); hi[1] = (short)h; lo[1] = (short)l;
    split2(p.z, h, l); hi[2] = (short)h; lo[2] = (short)l;
    split2(p.w, h, l); hi[3] = (short)h; lo[3] = (short)l;
    split2(q.x, h, l); hi[4] = (short)h; lo[4] = (short)l;
    split2(q.y, h, l); hi[5] = (short)h; lo[5] = (short)l;
    split2(q.z, h, l); hi[6] = (short)h; lo[6] = (short)l;
    split2(q.w, h, l); hi[7] = (short)h; lo[7] = (short)l;
}

// async global->LDS, 16B per lane. LDS dst is wave-uniform base; HW adds lane*16.
__device__ __forceinline__ void gload_lds16(const void* g, void* l) {
    __builtin_amdgcn_global_load_lds(
        (const __attribute__((address_space(1))) unsigned int*)g,
        (__attribute__((address_space(3))) unsigned int*)l, 16, 0, 0);
}

// ---------------------------------------------------------------------------
// K_setup: zero deg+cursor AND pre-split W1/W2 into bf16 hi/lo frag table,
// GROUP-MAJOR order: group g = kc*4+ks (16KB: 8 nf x {hi,lo} x 64 lanes x 16B)
//   frag_ab index = (g*16 + nf*2 + plane)*64 + lane
//   value(lane,j) = W[k = kc*128+ks*32+(lane>>4)*8+j][n = nf*16+(lane&15)]
// ---------------------------------------------------------------------------
__global__ __launch_bounds__(256) void setup_kernel(
    const float* __restrict__ W1, const float* __restrict__ W2,
    ushort* __restrict__ w1s, ushort* __restrict__ w2s, int* __restrict__ dz)
{
    int tg = blockIdx.x * 256 + threadIdx.x;
    if (tg < 2 * N_NODES) dz[tg] = 0;   // deg | cursor (contiguous)

    const float* W; ushort* out; int t;
    if (tg < 4096)      { W = W1; out = w1s; t = tg; }
    else if (tg < 6144) { W = W2; out = w2s; t = tg - 4096; }
    else return;

    int lane = t & 63;
    int ks   = (t >> 6) & 3;
    int nf   = (t >> 8) & 7;
    int kc   = t >> 11;            // 0..1 for W1, 0 for W2
    int k0   = kc * 128 + ks * 32 + (lane >> 4) * 8;
    int n    = nf * 16 + (lane & 15);

    frag_ab hi, lo;
    #pragma unroll
    for (int j = 0; j < 8; ++j) {
        ushort h, l;
        split2(W[(size_t)(k0 + j) * 128 + n], h, l);
        hi[j] = (short)h; lo[j] = (short)l;
    }
    size_t fi = ((size_t)(kc * 4 + ks) * 16 + nf * 2) * 64 + lane;
    ((frag_ab*)out)[fi]      = hi;
    ((frag_ab*)out)[fi + 64] = lo;
}

// ---------------------------------------------------------------------------
// CSR build chain
// ---------------------------------------------------------------------------
__global__ __launch_bounds__(256) void hist_kernel(const int* __restrict__ ei,
                                                   int* __restrict__ deg) {
    int t = blockIdx.x * 256 + threadIdx.x;
    if (t < N_EDGES) atomicAdd(&deg[ei[N_EDGES + t]], 1);
}

__global__ __launch_bounds__(256) void block_sum_kernel(const int* __restrict__ deg,
                                                        int* __restrict__ bsum) {
    __shared__ int s[256];
    int i = blockIdx.x * 256 + threadIdx.x;
    s[threadIdx.x] = (i < N_NODES) ? deg[i] : 0;
    __syncthreads();
    #pragma unroll
    for (int o = 128; o > 0; o >>= 1) {
        if (threadIdx.x < o) s[threadIdx.x] += s[threadIdx.x + o];
        __syncthreads();
    }
    if (threadIdx.x == 0) bsum[blockIdx.x] = s[0];
}

__global__ __launch_bounds__(512) void scan_bsum_kernel(const int* __restrict__ bsum,
                                                        int* __restrict__ bpre,
                                                        int* __restrict__ offsets) {
    __shared__ int bufA[512], bufB[512];
    int t = threadIdx.x;
    int v = (t < NSCAN_BLOCKS) ? bsum[t] : 0;
    bufA[t] = v;
    __syncthreads();
    int* src = bufA; int* dst = bufB;
    #pragma unroll
    for (int o = 1; o < 512; o <<= 1) {
        dst[t] = src[t] + ((t >= o) ? src[t - o] : 0);
        __syncthreads();
        int* tmp = src; src = dst; dst = tmp;
    }
    if (t < NSCAN_BLOCKS) bpre[t] = src[t] - v;   // exclusive
    if (t == 0) offsets[N_NODES] = N_EDGES;
}

__global__ __launch_bounds__(256) void scan_block_kernel(const int* __restrict__ deg,
                                                         const int* __restrict__ bpre,
                                                         int* __restrict__ offsets) {
    __shared__ int bufA[256], bufB[256];
    int t = threadIdx.x;
    int i = blockIdx.x * 256 + t;
    int v = (i < N_NODES) ? deg[i] : 0;
    bufA[t] = v;
    __syncthreads();
    int* src = bufA; int* dst = bufB;
    #pragma unroll
    for (int o = 1; o < 256; o <<= 1) {
        dst[t] = src[t] + ((t >= o) ? src[t - o] : 0);
        __syncthreads();
        int* tmp = src; src = dst; dst = tmp;
    }
    if (i < N_NODES) offsets[i] = bpre[blockIdx.x] + src[t] - v;
}

__global__ __launch_bounds__(256) void csr_scatter_kernel(const int* __restrict__ ei,
                                                          const int* __restrict__ offsets,
                                                          int* __restrict__ cursor,
                                                          int* __restrict__ csr) {
    int t = blockIdx.x * 256 + threadIdx.x;
    if (t < N_EDGES) {
        int src = ei[t];
        int dst = ei[N_EDGES + t];
        int pos = atomicAdd(&cursor[dst], 1);
        csr[offsets[dst] + pos] = src;
    }
}

// ---------------------------------------------------------------------------
// K1: h = LN(LeakyReLU(x @ W1 + b1)) via 3-term bf16-split MFMA.
// DEPTH-3 pipeline: 4x16KB LDS buffers; prologue issues groups 0..2; steady
// state {ISSUE(g+3); vmcnt(24)} -- 3 ISSUEs (24 VM ops) always in flight,
// tail counts down 16/8/0 (never draining early). 2 barriers/group.
// Block 256 = 4 waves x 32 rows (BM=128). 8 K-groups of 32.
// ---------------------------------------------------------------------------
__global__ __launch_bounds__(256, 2) void gemm1_ln_mfma_kernel(
    const float* __restrict__ x, const ushort* __restrict__ w1s,
    const float* __restrict__ b1, const float* __restrict__ gamma,
    const float* __restrict__ beta, float* __restrict__ h)
{
    __shared__ ushort sB[4][8192];   // 4 x 16KB

    const int tid  = threadIdx.x;
    const int lane = tid & 63;
    const int wv   = tid >> 6;          // wave id 0..3
    const int r16  = lane & 15;
    const int quad = lane >> 4;         // 0..3
    const int row0 = blockIdx.x * 128;

    const float* xrow[2];
    #pragma unroll
    for (int mf = 0; mf < 2; ++mf) {
        int r = row0 + wv * 32 + mf * 16 + r16;
        r = (r < N_NODES) ? r : (N_NODES - 1);
        xrow[mf] = x + (size_t)r * C_IN;
    }

    f32x4 acc[2][8];
    #pragma unroll
    for (int mf = 0; mf < 2; ++mf)
        #pragma unroll
        for (int nf = 0; nf < 8; ++nf)
            acc[mf][nf] = (f32x4){0.f, 0.f, 0.f, 0.f};

    float4 a[4][2][2];   // [buf][mf][half]

    auto ISSUE = [&](int g) {
        const int par = g & 3;
        const int col0 = (g >> 2) * 128 + (g & 3) * 32 + quad * 8;
        #pragma unroll
        for (int mf = 0; mf < 2; ++mf) {
            const float* xp = xrow[mf] + col0;
            a[par][mf][0] = *(const float4*)(xp);
            a[par][mf][1] = *(const float4*)(xp + 4);
        }
        const char* gsrc = (const char*)w1s + g * 16384 + wv * 4096 + lane * 16;
        char* ldst = (char*)&sB[par][0] + wv * 4096;
        #pragma unroll
        for (int it = 0; it < 4; ++it)
            gload_lds16(gsrc + it * 1024, ldst + it * 1024);
    };

    ISSUE(0); ISSUE(1); ISSUE(2);
    #pragma unroll
    for (int g = 0; g < 8; ++g) {
        if (g < 5) { ISSUE(g + 3); WAITV(24); }
        else if (g == 5) WAITV(16);
        else if (g == 6) WAITV(8);
        else             WAITV(0);
        __builtin_amdgcn_s_barrier();
        __builtin_amdgcn_sched_barrier(0);

        const int par = g & 3;
        frag_ab aHi[2], aLo[2];
        split8(a[par][0][0], a[par][0][1], aHi[0], aLo[0]);
        split8(a[par][1][0], a[par][1][1], aHi[1], aLo[1]);
        const char* bb = (const char*)&sB[par][0] + lane * 16;
        #pragma unroll
        for (int nf = 0; nf < 8; ++nf) {
            frag_ab bHi = *(const frag_ab*)(bb + nf * 2048);
            frag_ab bLo = *(const frag_ab*)(bb + nf * 2048 + 1024);
            acc[0][nf] = __builtin_amdgcn_mfma_f32_16x16x32_bf16(aHi[0], bHi, acc[0][nf], 0, 0, 0);
            acc[0][nf] = __builtin_amdgcn_mfma_f32_16x16x32_bf16(aLo[0], bHi, acc[0][nf], 0, 0, 0);
            acc[0][nf] = __builtin_amdgcn_mfma_f32_16x16x32_bf16(aHi[0], bLo, acc[0][nf], 0, 0, 0);
            acc[1][nf] = __builtin_amdgcn_mfma_f32_16x16x32_bf16(aHi[1], bHi, acc[1][nf], 0, 0, 0);
            acc[1][nf] = __builtin_amdgcn_mfma_f32_16x16x32_bf16(aLo[1], bHi, acc[1][nf], 0, 0, 0);
            acc[1][nf] = __builtin_amdgcn_mfma_f32_16x16x32_bf16(aHi[1], bLo, acc[1][nf], 0, 0, 0);
        }
        __builtin_amdgcn_sched_barrier(0);
        __builtin_amdgcn_s_barrier();
    }

    // ---- epilogue: +b1, LeakyReLU, LayerNorm, store h ----
    float b1v[8], gv[8], bv[8];
    #pragma unroll
    for (int nf = 0; nf < 8; ++nf) {
        int cidx = nf * 16 + r16;
        b1v[nf] = b1[cidx]; gv[nf] = gamma[cidx]; bv[nf] = beta[cidx];
    }

    #pragma unroll
    for (int mf = 0; mf < 2; ++mf)
        #pragma unroll
        for (int nf = 0; nf < 8; ++nf)
            #pragma unroll
            for (int rg = 0; rg < 4; ++rg) {
                float v = acc[mf][nf][rg] + b1v[nf];
                acc[mf][nf][rg] = (v > 0.f) ? v : NEG_SLOPE * v;
            }

    #pragma unroll
    for (int mf = 0; mf < 2; ++mf) {
        #pragma unroll
        for (int rg = 0; rg < 4; ++rg) {
            float s = 0.f, ss = 0.f;
            #pragma unroll
            for (int nf = 0; nf < 8; ++nf) {
                float v = acc[mf][nf][rg];
                s += v; ss += v * v;
            }
            #pragma unroll
            for (int m = 1; m < 16; m <<= 1) {
                s  += __shfl_xor(s,  m, 64);
                ss += __shfl_xor(ss, m, 64);
            }
            float mu   = s * (1.f / C_HID);
            float var  = ss * (1.f / C_HID) - mu * mu;
            float rstd = rsqrtf(var + LN_EPS);
            int row = row0 + wv * 32 + mf * 16 + (quad << 2) + rg;
            if (row < N_NODES) {
                #pragma unroll
                for (int nf = 0; nf < 8; ++nf) {
                    float o = (acc[mf][nf][rg] - mu) * rstd * gv[nf] + bv[nf];
                    h[(size_t)row * C_HID + nf * 16 + r16] = o;
                }
            }
        }
    }
}

// ---------------------------------------------------------------------------
// K2: gather-min, one wave per node; 8-deep independent-load batches
// (mean degree 6 -> whole node in ONE batch; all guards wave-uniform).
// ---------------------------------------------------------------------------
__global__ __launch_bounds__(256) void gather_min_kernel(
    const float* __restrict__ h, const int* __restrict__ offsets,
    const int* __restrict__ csr, float* __restrict__ agg)
{
    const int lane = threadIdx.x & 63;
    const int row  = blockIdx.x * 4 + (threadIdx.x >> 6);
    if (row >= N_NODES) return;

    const int beg = offsets[row];
    const int end = offsets[row + 1];

    float m0 = INFINITY, m1 = INFINITY;

    for (int j0 = beg; j0 < end; j0 += 64) {
        const int cnt = min(64, end - j0);   // wave-uniform
        int idx = (lane < cnt) ? csr[j0 + lane] : 0;
        for (int k = 0; k < cnt; k += 8) {
            float2 v[8];
            #pragma unroll
            for (int i = 0; i < 8; ++i) {
                int kk = k + i;
                int s = __shfl(idx, (kk < cnt) ? kk : 0);
                if (kk < cnt)
                    v[i] = ((const float2*)(h + (size_t)s * C_HID))[lane];
                else
                    v[i] = make_float2(INFINITY, INFINITY);
            }
            #pragma unroll
            for (int i = 0; i < 8; ++i) {
                m0 = fminf(m0, v[i].x);
                m1 = fminf(m1, v[i].y);
            }
        }
    }

    if (m0 == INFINITY) m0 = 0.f;   // empty segment -> 0 (PyG fill; h is finite)
    if (m1 == INFINITY) m1 = 0.f;
    ((float2*)(agg + (size_t)row * C_HID))[lane] = make_float2(m0, m1);
}

// ---------------------------------------------------------------------------
// K3: out = agg @ W2 + b2 via 3-term bf16-split MFMA, DEPTH-3 pipeline
// (4 K-groups; only one latency-exposed wait at g=0).
// ---------------------------------------------------------------------------
__global__ __launch_bounds__(256, 2) void gemm2_mfma_kernel(
    const float* __restrict__ agg, const ushort* __restrict__ w2s,
    const float* __restrict__ b2, float* __restrict__ out)
{
    __shared__ ushort sB[4][8192];

    const int tid  = threadIdx.x;
    const int lane = tid & 63;
    const int wv   = tid >> 6;
    const int r16  = lane & 15;
    const int quad = lane >> 4;
    const int row0 = blockIdx.x * 128;

    const float* arow[2];
    #pragma unroll
    for (int mf = 0; mf < 2; ++mf) {
        int r = row0 + wv * 32 + mf * 16 + r16;
        r = (r < N_NODES) ? r : (N_NODES - 1);
        arow[mf] = agg + (size_t)r * C_HID;
    }

    f32x4 acc[2][8];
    #pragma unroll
    for (int mf = 0; mf < 2; ++mf)
        #pragma unroll
        for (int nf = 0; nf < 8; ++nf)
            acc[mf][nf] = (f32x4){0.f, 0.f, 0.f, 0.f};

    float4 a[4][2][2];

    auto ISSUE = [&](int g) {
        const int par = g & 3;
        const int col0 = g * 32 + quad * 8;
        #pragma unroll
        for (int mf = 0; mf < 2; ++mf) {
            const float* ap = arow[mf] + col0;
            a[par][mf][0] = *(const float4*)(ap);
            a[par][mf][1] = *(const float4*)(ap + 4);
        }
        const char* gsrc = (const char*)w2s + g * 16384 + wv * 4096 + lane * 16;
        char* ldst = (char*)&sB[par][0] + wv * 4096;
        #pragma unroll
        for (int it = 0; it < 4; ++it)
            gload_lds16(gsrc + it * 1024, ldst + it * 1024);
    };

    ISSUE(0); ISSUE(1); ISSUE(2);
    #pragma unroll
    for (int g = 0; g < 4; ++g) {
        if (g == 0) { ISSUE(3); WAITV(24); }
        else if (g == 1) WAITV(16);
        else if (g == 2) WAITV(8);
        else             WAITV(0);
        __builtin_amdgcn_s_barrier();
        __builtin_amdgcn_sched_barrier(0);

        const int par = g & 3;
        frag_ab aHi[2], aLo[2];
        split8(a[par][0][0], a[par][0][1], aHi[0], aLo[0]);
        split8(a[par][1][0], a[par][1][1], aHi[1], aLo[1]);
        const char* bb = (const char*)&sB[par][0] + lane * 16;
        #pragma unroll
        for (int nf = 0; nf < 8; ++nf) {
            frag_ab bHi = *(const frag_ab*)(bb + nf * 2048);
            frag_ab bLo = *(const frag_ab*)(bb + nf * 2048 + 1024);
            acc[0][nf] = __builtin_amdgcn_mfma_f32_16x16x32_bf16(aHi[0], bHi, acc[0][nf], 0, 0, 0);
            acc[0][nf] = __builtin_amdgcn_mfma_f32_16x16x32_bf16(aLo[0], bHi, acc[0][nf], 0, 0, 0);
            acc[0][nf] = __builtin_amdgcn_mfma_f32_16x16x32_bf16(aHi[0], bLo, acc[0][nf], 0, 0, 0);
            acc[1][nf] = __builtin_amdgcn_mfma_f32_16x16x32_bf16(aHi[1], bHi, acc[1][nf], 0, 0, 0);
            acc[1][nf] = __builtin_amdgcn_mfma_f32_16x16x32_bf16(aLo[1], bHi, acc[1][nf], 0, 0, 0);
            acc[1][nf] = __builtin_amdgcn_mfma_f32_16x16x32_bf16(aHi[1], bLo, acc[1][nf], 0, 0, 0);
        }
        __builtin_amdgcn_sched_barrier(0);
        __builtin_amdgcn_s_barrier();
    }

    float b2v[8];
    #pragma unroll
    for (int nf = 0; nf < 8; ++nf) b2v[nf] = b2[nf * 16 + r16];

    #pragma unroll
    for (int mf = 0; mf < 2; ++mf) {
        #pragma unroll
        for (int rg = 0; rg < 4; ++rg) {
            int row = row0 + wv * 32 + mf * 16 + (quad << 2) + rg;
            if (row < N_NODES) {
                #pragma unroll
                for (int nf = 0; nf < 8; ++nf)
                    out[(size_t)row * C_OUT + nf * 16 + r16] = acc[mf][nf][rg] + b2v[nf];
            }
        }
    }
}

// ---------------------------------------------------------------------------
extern "C" void kernel_launch(void* const* d_in, const int* in_sizes, int n_in,
                              void* d_out, int out_size, void* d_ws, size_t ws_size,
                              hipStream_t stream)
{
    const float* x     = (const float*)d_in[0];
    const int*   ei    = (const int*)d_in[3];   // [2, E] row-major int32
    const float* W1    = (const float*)d_in[4];
    const float* b1    = (const float*)d_in[5];
    const float* gamma = (const float*)d_in[6];
    const float* beta  = (const float*)d_in[7];
    const float* W2    = (const float*)d_in[8];
    const float* b2    = (const float*)d_in[9];
    float*       out   = (float*)d_out;

    // ws: h 51.2MB | agg 51.2MB | deg | cursor | offsets | bsum | bpre | csr | w1s 128KB | w2s 64KB
    char* p = (char*)d_ws;
    float*  h       = (float*)p;           p += (size_t)N_NODES * C_HID * 4;
    float*  agg     = (float*)p;           p += (size_t)N_NODES * C_HID * 4;
    int*    deg     = (int*)p;             p += 400000;   // cursor follows contiguously
    int*    cursor  = (int*)p;             p += 400000;
    int*    offsets = (int*)p;             p += 400016;   // 100001 ints, padded
    int*    bsum    = (int*)p;             p += 1600;
    int*    bpre    = (int*)p;             p += 1600;
    int*    csr     = (int*)p;             p += (size_t)N_EDGES * 4;
    ushort* w1s     = (ushort*)p;          p += 131072;
    ushort* w2s     = (ushort*)p;

    const int grid_e    = (N_EDGES + 255) / 256;   // 2344
    const int grid_gemm = (N_NODES + 127) / 128;   // 782

    setup_kernel<<<grid_gemm, 256, 0, stream>>>(W1, W2, w1s, w2s, deg);
    hist_kernel<<<grid_e, 256, 0, stream>>>(ei, deg);
    block_sum_kernel<<<NSCAN_BLOCKS, 256, 0, stream>>>(deg, bsum);
    scan_bsum_kernel<<<1, 512, 0, stream>>>(bsum, bpre, offsets);
    scan_block_kernel<<<NSCAN_BLOCKS, 256, 0, stream>>>(deg, bpre, offsets);
    csr_scatter_kernel<<<grid_e, 256, 0, stream>>>(ei, offsets, cursor, csr);
    gemm1_ln_mfma_kernel<<<grid_gemm, 256, 0, stream>>>(x, w1s, b1, gamma, beta, h);
    gather_min_kernel<<<(N_NODES + 3) / 4, 256, 0, stream>>>(h, offsets, csr, agg);
    gemm2_mfma_kernel<<<grid_gemm, 256, 0, stream>>>(agg, w2s, b2, out);
}